// Round 1
// baseline (355.998 us; speedup 1.0000x reference)
//
#include <hip/hip_runtime.h>

// y = W @ x + b
// W: fp32 [8192, 8192] row-major (256 MiB) — the entire traffic
// x: fp32 [8192], b: fp32 [8192], y: fp32 [8192]
//
// One 64-lane wave per output row. float4 coalesced loads of the W row,
// dot with x (L1/L2 resident), shuffle-reduce, lane 0 writes y[row]+b[row].

constexpr int IN_F  = 8192;
constexpr int OUT_F = 8192;
constexpr int WAVES_PER_BLOCK = 4;   // 256 threads

__global__ __launch_bounds__(256) void matvec_f32_kernel(
    const float* __restrict__ x,
    const float* __restrict__ W,
    const float* __restrict__ b,
    float* __restrict__ y) {

  const int lane = threadIdx.x & 63;
  const int wave = threadIdx.x >> 6;
  const int row  = blockIdx.x * WAVES_PER_BLOCK + wave;

  const float4* __restrict__ Wrow = reinterpret_cast<const float4*>(
      W + (size_t)row * IN_F);
  const float4* __restrict__ xv = reinterpret_cast<const float4*>(x);

  float acc = 0.0f;
  // IN_F/4 = 2048 float4 per row; 64 lanes -> 32 iterations
#pragma unroll 4
  for (int i = lane; i < IN_F / 4; i += 64) {
    float4 w  = Wrow[i];
    float4 xx = xv[i];
    acc += w.x * xx.x + w.y * xx.y + w.z * xx.z + w.w * xx.w;
  }

  // 64-lane butterfly reduction
#pragma unroll
  for (int off = 32; off > 0; off >>= 1)
    acc += __shfl_down(acc, off, 64);

  if (lane == 0) y[row] = acc + b[row];
}

extern "C" void kernel_launch(void* const* d_in, const int* in_sizes, int n_in,
                              void* d_out, int out_size, void* d_ws, size_t ws_size,
                              hipStream_t stream) {
  const float* x = (const float*)d_in[0];   // input  [8192]
  const float* W = (const float*)d_in[1];   // weight [8192*8192]
  const float* b = (const float*)d_in[2];   // bias   [8192]
  float* y = (float*)d_out;                 // output [8192] fp32

  dim3 grid(OUT_F / WAVES_PER_BLOCK);       // 2048 blocks
  dim3 block(WAVES_PER_BLOCK * 64);         // 256 threads
  matvec_f32_kernel<<<grid, block, 0, stream>>>(x, W, b, y);
}

// Round 2
// 354.269 us; speedup vs baseline: 1.0049x; 1.0049x over previous
//
#include <hip/hip_runtime.h>

// y = W @ x + b
// W: fp32 [8192, 8192] row-major (256 MiB) — sole HBM traffic, streamed once.
// x: fp32 [8192] (32 KB) — staged into LDS once per block, reused by all 4 waves.
// One 64-lane wave per output row; batches of 8 global_load_dwordx4 for MLP.

constexpr int IN_F  = 8192;
constexpr int OUT_F = 8192;
constexpr int WAVES_PER_BLOCK = 4;   // 256 threads

__global__ __launch_bounds__(256) void matvec_f32_kernel(
    const float* __restrict__ x,
    const float* __restrict__ W,
    const float* __restrict__ b,
    float* __restrict__ y) {

  __shared__ float4 xs[IN_F / 4];    // 32 KB LDS

  const int tid = threadIdx.x;
  const float4* __restrict__ xv = reinterpret_cast<const float4*>(x);

  // Stage x into LDS: 2048 float4 / 256 threads = 8 coalesced iterations.
#pragma unroll
  for (int i = 0; i < (IN_F / 4) / 256; ++i)
    xs[tid + i * 256] = xv[tid + i * 256];
  __syncthreads();

  const int lane = tid & 63;
  const int wave = tid >> 6;
  const int row  = blockIdx.x * WAVES_PER_BLOCK + wave;

  const float4* __restrict__ Wrow = reinterpret_cast<const float4*>(
      W + (size_t)row * IN_F);

  // 2048 float4 per row / 64 lanes = 32 iterations; grouped 8-deep for MLP.
  float a0 = 0.f, a1 = 0.f, a2 = 0.f, a3 = 0.f;
#pragma unroll
  for (int it = 0; it < 4; ++it) {
    float4 w[8];
#pragma unroll
    for (int j = 0; j < 8; ++j)
      w[j] = Wrow[lane + (it * 8 + j) * 64];   // 8 KB of W in flight per wave
#pragma unroll
    for (int j = 0; j < 8; ++j) {
      float4 xx = xs[lane + (it * 8 + j) * 64];
      a0 += w[j].x * xx.x;
      a1 += w[j].y * xx.y;
      a2 += w[j].z * xx.z;
      a3 += w[j].w * xx.w;
    }
  }
  float acc = (a0 + a1) + (a2 + a3);

  // 64-lane butterfly reduction
#pragma unroll
  for (int off = 32; off > 0; off >>= 1)
    acc += __shfl_down(acc, off, 64);

  if (lane == 0) y[row] = acc + b[row];
}

extern "C" void kernel_launch(void* const* d_in, const int* in_sizes, int n_in,
                              void* d_out, int out_size, void* d_ws, size_t ws_size,
                              hipStream_t stream) {
  const float* x = (const float*)d_in[0];   // input  [8192]
  const float* W = (const float*)d_in[1];   // weight [8192*8192]
  const float* b = (const float*)d_in[2];   // bias   [8192]
  float* y = (float*)d_out;                 // output [8192] fp32

  dim3 grid(OUT_F / WAVES_PER_BLOCK);       // 2048 blocks -> 8 blocks/CU
  dim3 block(WAVES_PER_BLOCK * 64);         // 256 threads (4 waves)
  matvec_f32_kernel<<<grid, block, 0, stream>>>(x, W, b, y);
}

// Round 3
// 333.715 us; speedup vs baseline: 1.0668x; 1.0616x over previous
//
#include <hip/hip_runtime.h>

// y = W @ x + b ; W fp32 [8192,8192] (256 MiB) streamed once in memcpy order.
//
// Each block owns ROWS_PER_BLOCK=4 consecutive rows = one contiguous 128 KB
// chunk, read in pure sequential order (thread t, step s -> float4 t+256s),
// i.e. a 4-KB sliding front per block like a memcpy/fill kernel.
// Since col4 = (t+256s) mod 2048 = t + 256*(s mod 8), each thread needs only
// 8 x-float4s, kept in registers and reused for all 4 rows. No LDS staging.
// W loads are nontemporal (zero reuse). Per-row wave shuffle-reduce + 64 B
// LDS cross-wave reduction.

constexpr int IN_F  = 8192;
constexpr int OUT_F = 8192;
constexpr int ROWS_PER_BLOCK = 4;
constexpr int NT = 256;                 // threads per block (4 waves)
constexpr int C4 = IN_F / 4;            // 2048 float4 per row

typedef float v4f __attribute__((ext_vector_type(4)));

__global__ __launch_bounds__(NT) void matvec_f32_kernel(
    const float* __restrict__ x,
    const float* __restrict__ W,
    const float* __restrict__ bias,
    float* __restrict__ y) {

  const int t = threadIdx.x;
  const int blk = blockIdx.x;

  const v4f* __restrict__ xv = reinterpret_cast<const v4f*>(x);
  const v4f* __restrict__ Wc = reinterpret_cast<const v4f*>(
      W + (size_t)blk * ROWS_PER_BLOCK * IN_F);

  // Per-thread x fragment: 8 float4 (coalesced, L2-resident), reused 4x.
  v4f xf[8];
#pragma unroll
  for (int j = 0; j < 8; ++j)
    xf[j] = xv[t + 256 * j];

  float acc[ROWS_PER_BLOCK];

#pragma unroll
  for (int r = 0; r < ROWS_PER_BLOCK; ++r) {
    // 8 nontemporal dwordx4 in flight (8 KB/wave), memcpy-ordered.
    v4f w[8];
#pragma unroll
    for (int j = 0; j < 8; ++j)
      w[j] = __builtin_nontemporal_load(&Wc[t + 256 * (8 * r + j)]);

    float p0 = 0.f, p1 = 0.f;
#pragma unroll
    for (int j = 0; j < 8; ++j) {
      p0 += w[j].x * xf[j].x + w[j].z * xf[j].z;
      p1 += w[j].y * xf[j].y + w[j].w * xf[j].w;
    }
    acc[r] = p0 + p1;
  }

  // Reduce each row across the wave, then across the 4 waves via LDS.
  __shared__ float red[4][ROWS_PER_BLOCK];
  const int lane = t & 63;
  const int wave = t >> 6;

#pragma unroll
  for (int r = 0; r < ROWS_PER_BLOCK; ++r) {
    float v = acc[r];
#pragma unroll
    for (int off = 32; off > 0; off >>= 1)
      v += __shfl_down(v, off, 64);
    if (lane == 0) red[wave][r] = v;
  }
  __syncthreads();

  if (t < ROWS_PER_BLOCK) {
    float v = red[0][t] + red[1][t] + red[2][t] + red[3][t];
    y[blk * ROWS_PER_BLOCK + t] = v + bias[blk * ROWS_PER_BLOCK + t];
  }
}

extern "C" void kernel_launch(void* const* d_in, const int* in_sizes, int n_in,
                              void* d_out, int out_size, void* d_ws, size_t ws_size,
                              hipStream_t stream) {
  const float* x = (const float*)d_in[0];   // input  [8192]
  const float* W = (const float*)d_in[1];   // weight [8192*8192]
  const float* b = (const float*)d_in[2];   // bias   [8192]
  float* y = (float*)d_out;                 // output [8192] fp32

  dim3 grid(OUT_F / ROWS_PER_BLOCK);        // 2048 blocks
  dim3 block(NT);                           // 256 threads
  matvec_f32_kernel<<<grid, block, 0, stream>>>(x, W, b, y);
}